// Round 1
// baseline (356.708 us; speedup 1.0000x reference)
//
#include <hip/hip_runtime.h>

// GD_13907104105202: x_K for x <- x - s*(Wx - b), x0=0, K=20, s=1e-6.
// Closed form: x_K = s * sum_{m=0}^{19} C(20,m+1) (-s)^m W^m b.
// m>=2 terms are below fp32 ulp of the result (~3e-12 vs result ~9e-5),
// so x = 20*s*b - 190*s^2*(W b) is exact to fp32 roundoff.
// One batched matvec: memory-bound on reading W once (268 MB, ~45us @ 6 TB/s).

constexpr int Bsz = 256;
constexpr int N   = 512;
constexpr int BLOCKS_PER_BATCH = 4;
constexpr int ROWS_PER_BLOCK   = N / BLOCKS_PER_BATCH;  // 128
constexpr int THREADS = 256;                             // 4 waves

__global__ __launch_bounds__(THREADS) void gd_closed_form(
    const float* __restrict__ W,     // [B, N, N] row-major
    const float* __restrict__ bv,    // [B, N]
    const float* __restrict__ sptr,  // scalar step size
    float* __restrict__ out)         // [B, N]
{
    __shared__ float sb[N];

    const int batch = blockIdx.x >> 2;   // / BLOCKS_PER_BATCH
    const int slice = blockIdx.x & 3;
    const int row0  = slice * ROWS_PER_BLOCK;

    const float s  = *sptr;
    const float c0 = 20.0f * s;          // coefficient of b
    const float c1 = 190.0f * s * s;     // coefficient of W b

    // Stage b[batch] (512 floats) into LDS: 256 threads x float2.
    const float* bb = bv + (size_t)batch * N;
    ((float2*)sb)[threadIdx.x] = ((const float2*)bb)[threadIdx.x];
    __syncthreads();

    const int wave = threadIdx.x >> 6;
    const int lane = threadIdx.x & 63;

    // Each lane's two b fragments (hoisted: reused for every row).
    const float4* sb4 = (const float4*)sb;
    const float4 b0 = sb4[lane];        // cols [4*lane, 4*lane+3]
    const float4 b1 = sb4[64 + lane];   // cols [256+4*lane, ...]

    const float4* Wb = (const float4*)(W + (size_t)batch * N * N);

    // 4 waves interleave over 128 rows: wave w takes rows row0 + w + 4*r.
#pragma unroll 2
    for (int r = 0; r < ROWS_PER_BLOCK / 4; ++r) {
        const int row = row0 + wave + 4 * r;
        const float4* Wrow = Wb + (size_t)row * (N / 4);
        const float4 w0 = Wrow[lane];
        const float4 w1 = Wrow[64 + lane];

        float acc = w0.x * b0.x + w0.y * b0.y + w0.z * b0.z + w0.w * b0.w
                  + w1.x * b1.x + w1.y * b1.y + w1.z * b1.z + w1.w * b1.w;

        // 64-lane wave reduction.
#pragma unroll
        for (int off = 32; off > 0; off >>= 1)
            acc += __shfl_down(acc, off);

        if (lane == 0)
            out[(size_t)batch * N + row] = c0 * sb[row] - c1 * acc;
    }
}

extern "C" void kernel_launch(void* const* d_in, const int* in_sizes, int n_in,
                              void* d_out, int out_size, void* d_ws, size_t ws_size,
                              hipStream_t stream) {
    const float* W  = (const float*)d_in[0];
    const float* bv = (const float*)d_in[1];
    const float* s  = (const float*)d_in[2];
    float* out      = (float*)d_out;

    dim3 grid(Bsz * BLOCKS_PER_BATCH);
    dim3 block(THREADS);
    gd_closed_form<<<grid, block, 0, stream>>>(W, bv, s, out);
}